// Round 2
// baseline (1022.700 us; speedup 1.0000x reference)
//
#include <hip/hip_runtime.h>
#include <stdint.h>

// Chebyshev GCN: out[b,n,o,t] = relu( sum_{k,c,m} cheb[k,m,n]*STDG[b,m,n]*x[b,m,c,t]*theta[k,c,o] )
// Restructured as, per b:  C[n, j] = relu( sum_p A[p,n] * Y[p,j] ),  p=(k,m) in [0,3072), j=o*24+t
//   A[p,n] = cheb[k,m,n]*STDG[b,m,n]          (kprepA: split bf16 hi/lo, stored [bb][n][p])
//   Y[p,j] = sum_c theta[k,c,o]*x[b,m,c,t]    (kprepY: split bf16 hi/lo, [bb][p][j]; ktransY -> [bb][j][p])
// GEMM uses 3-term split-bf16 MFMA (AhYh + AlYh + AhYl) -> ~3e-5 relative error (fp32-equivalent).
// Round-2 change: batch-chunked adaptive workspace (NB in {16,8,4,2,1}; 40.9 MB per b) since
// round 1's abort is most consistent with ws_size < the 654 MB I blindly assumed.

#define BB   16
#define NN   1024
#define CIN  64
#define TT   24
#define KCH  3
#define COUT 64
#define PP   (KCH*NN)    // 3072 contraction length
#define JJ   (COUT*TT)   // 1536 output columns per n

typedef __attribute__((ext_vector_type(4))) float f32x4;
typedef __attribute__((ext_vector_type(8))) short bf16x8;

typedef __attribute__((address_space(1))) const unsigned int* gas_cuintp;
typedef __attribute__((address_space(3))) unsigned int* las_uintp;

static __device__ __forceinline__ unsigned short f2bf(float f){
  union { float f; unsigned u; } v; v.f = f;
  unsigned r = v.u + 0x7fffu + ((v.u >> 16) & 1u);   // round-to-nearest-even
  return (unsigned short)(r >> 16);
}
static __device__ __forceinline__ float bf2f(unsigned short h){
  union { float f; unsigned u; } v; v.u = ((unsigned)h) << 16; return v.f;
}

// ---------------- K0: A-prep  (masked = cheb*STDG, split, transpose to [bb][n][p]) ----------------
__global__ __launch_bounds__(256) void kprepA(const float* __restrict__ cheb,
                                              const float* __restrict__ stdg,
                                              unsigned short* __restrict__ Ah,
                                              unsigned short* __restrict__ Al,
                                              int b0){
  int nt = blockIdx.x;             // 16 n-tiles of 64
  int mt = blockIdx.y;             // 16 m-tiles of 64
  int bk = blockIdx.z;             // NB*3 = bb*3+k
  int bb = bk / 3, k = bk - bb * 3;
  int b = b0 + bb;
  __shared__ float alds[64][65];   // [n][m], padded
  int tid = threadIdx.x;
  {
    int rm = tid >> 2;             // m row 0..63
    int nc = (tid & 3) << 4;       // n col group
    const float* cp = cheb + ((size_t)(k*NN + mt*64 + rm))*NN + nt*64 + nc;
    const float* sp = stdg + ((size_t)(b*NN + mt*64 + rm))*NN + nt*64 + nc;
    #pragma unroll
    for (int i = 0; i < 16; i += 4){
      f32x4 cv = *(const f32x4*)(cp + i);
      f32x4 sv = *(const f32x4*)(sp + i);
      #pragma unroll
      for (int q = 0; q < 4; q++) alds[nc + i + q][rm] = cv[q] * sv[q];
    }
  }
  __syncthreads();
  {
    int rn = tid >> 2;             // n row 0..63
    int mc = (tid & 3) << 4;       // m col group
    union { unsigned short s[16]; uint4 v[2]; } hb, lb;
    #pragma unroll
    for (int i = 0; i < 16; i++){
      float a = alds[rn][mc + i];
      unsigned short h = f2bf(a);
      hb.s[i] = h;
      lb.s[i] = f2bf(a - bf2f(h));
    }
    size_t ob = ((size_t)(bb*NN + nt*64 + rn))*PP + (size_t)k*NN + mt*64 + mc;
    *(uint4*)(Ah + ob)     = hb.v[0];
    *(uint4*)(Ah + ob + 8) = hb.v[1];
    *(uint4*)(Al + ob)     = lb.v[0];
    *(uint4*)(Al + ob + 8) = lb.v[1];
  }
}

// ---------------- K1: Y-prep (theta-apply over c, split, store [bb][p][j]) ----------------
// LDS = 24 KiB x-slab (c-chunked, 2 passes) + 24 KiB theta = 48 KiB.
__global__ __launch_bounds__(256) void kprepY(const float* __restrict__ x,
                                              const float* __restrict__ theta,
                                              unsigned short* __restrict__ Yh,
                                              unsigned short* __restrict__ Yl,
                                              int b0){
  int oh = blockIdx.x & 1;         // o-half (32 outputs)
  int mt = blockIdx.x >> 1;        // 0..127, 8 m's each
  int bb = blockIdx.y;
  int b  = b0 + bb;
  __shared__ float xs[8][32][24];  // 24 KiB, x slab (half the c-range)
  __shared__ float ths[3][64][32]; // 24 KiB, theta half
  int tid = threadIdx.x;
  float* thf = &ths[0][0][0];
  for (int i = tid; i < 3*64*32; i += 256){
    int row = i >> 5;              // k*64 + c
    int col = i & 31;
    thf[i] = theta[row*64 + oh*32 + col];
  }
  int mi = tid >> 5, oi = tid & 31;
  float acc0[24], acc1[24], acc2[24];
  #pragma unroll
  for (int t = 0; t < 24; t++){ acc0[t]=0.f; acc1[t]=0.f; acc2[t]=0.f; }
  const f32x4* xg = (const f32x4*)(x + ((size_t)(b*NN + mt*8))*CIN*TT);
  for (int cc = 0; cc < 2; cc++){
    __syncthreads();               // first iter: theta ready; later: xs consumed
    f32x4* xsv = (f32x4*)&xs[0][0][0];
    for (int i4 = tid; i4 < 1536; i4 += 256){
      int m = i4 / 192, r4 = i4 - m*192;
      xsv[i4] = xg[m*384 + cc*192 + r4];
    }
    __syncthreads();
    for (int c = 0; c < 32; c++){
      float xv[24];
      #pragma unroll
      for (int q = 0; q < 6; q++) *(f32x4*)&xv[q*4] = *(const f32x4*)&xs[mi][c][q*4];
      int cg = cc*32 + c;
      float t0 = ths[0][cg][oi], t1 = ths[1][cg][oi], t2 = ths[2][cg][oi];
      #pragma unroll
      for (int t = 0; t < 24; t++){
        acc0[t] = fmaf(t0, xv[t], acc0[t]);
        acc1[t] = fmaf(t1, xv[t], acc1[t]);
        acc2[t] = fmaf(t2, xv[t], acc2[t]);
      }
    }
  }
  #pragma unroll
  for (int k = 0; k < 3; k++){
    const float* a = (k==0) ? acc0 : (k==1) ? acc1 : acc2;  // k is unroll-constant
    union { unsigned short s[24]; uint4 v[3]; } hb, lb;
    #pragma unroll
    for (int t = 0; t < 24; t++){
      unsigned short h = f2bf(a[t]);
      hb.s[t] = h;
      lb.s[t] = f2bf(a[t] - bf2f(h));
    }
    size_t ob = ((size_t)bb*PP + (size_t)k*NN + mt*8 + mi)*JJ + (size_t)(oh*32 + oi)*TT;
    *(uint4*)(Yh + ob)      = hb.v[0];
    *(uint4*)(Yh + ob + 8)  = hb.v[1];
    *(uint4*)(Yh + ob + 16) = hb.v[2];
    *(uint4*)(Yl + ob)      = lb.v[0];
    *(uint4*)(Yl + ob + 8)  = lb.v[1];
    *(uint4*)(Yl + ob + 16) = lb.v[2];
  }
}

// ---------------- K1.5: bulk transpose [bb][p][j] -> [bb][j][p] (64x64 bf16 tiles) ----------------
__global__ __launch_bounds__(256) void ktransY(const unsigned short* __restrict__ in,
                                               unsigned short* __restrict__ out){
  int jt = blockIdx.x;  // 24 tiles of 64 j
  int pt = blockIdx.y;  // 48 tiles of 64 p
  int bb = blockIdx.z;
  __shared__ unsigned uls[64][33];  // [p][j-pair], padded
  int tid = threadIdx.x;
  int r  = tid >> 5;     // 0..7
  int cq = tid & 31;     // 0..31
  #pragma unroll
  for (int i = 0; i < 8; i++){
    int p = r + i*8;
    uls[p][cq] = *(const unsigned*)(in + ((size_t)bb*PP + pt*64 + p)*JJ + jt*64 + cq*2);
  }
  __syncthreads();
  #pragma unroll
  for (int i = 0; i < 8; i++){
    int j = r + i*8;
    unsigned w0 = uls[cq*2][j>>1];
    unsigned w1 = uls[cq*2+1][j>>1];
    unsigned e0 = (j & 1) ? (w0 >> 16) : (w0 & 0xffffu);
    unsigned e1 = (j & 1) ? (w1 >> 16) : (w1 & 0xffffu);
    *(unsigned*)(out + ((size_t)bb*JJ + jt*64 + j)*PP + pt*64 + cq*2) = e0 | (e1 << 16);
  }
}

// ---------------- K2: per-b GEMM  C[n,j] = relu(sum_p A[p,n]*Y[p,j]), split-bf16 3-MFMA ----------------
// Tiles: BM=128 (n) x BN=128 (j) x BK=64 (p). 4 waves (2x2), wave-tile 64x64.
// LDS 4 x [128 rows][64 bf16] = 64 KiB, single-buffered, global_load_lds w/ pre-swizzled source.
__global__ __launch_bounds__(256, 2) void kgemm(
    const unsigned short* __restrict__ Ah, const unsigned short* __restrict__ Al,
    const unsigned short* __restrict__ Yh, const unsigned short* __restrict__ Yl,
    float* __restrict__ out, int b0){
  __shared__ unsigned short AhL[128*64];
  __shared__ unsigned short AlL[128*64];
  __shared__ unsigned short YhL[128*64];
  __shared__ unsigned short YlL[128*64];
  int orig = blockIdx.x;
  int cpx  = (int)(gridDim.x >> 3);              // grid is NB*96, always % 8 == 0 -> bijective
  int wgid = ((orig & 7) * cpx) + (orig >> 3);   // XCD swizzle
  int bb  = wgid / 96;
  int r96 = wgid - bb*96;
  int nt  = r96 / 12;
  int jt  = r96 - nt*12;
  int tid = threadIdx.x;
  int lane = tid & 63, wave = tid >> 6;
  int wr = wave >> 1, wc = wave & 1;

  // staging: 4 tiles x 1024 chunks(16B) each; thread handles chunk (tid + it*256) of every tile.
  // source chunk index pre-swizzled: sc = c8 ^ (row&7) so LDS slot s holds global chunk s^(row&7).
  unsigned aoff[4], yoff[4];
  #pragma unroll
  for (int it = 0; it < 4; it++){
    int c = tid + it*256;
    int row = c >> 3;
    int sc = (c & 7) ^ (row & 7);
    aoff[it] = (unsigned)(((bb*NN + nt*128 + row) * PP) * 2 + sc * 16);
    yoff[it] = (unsigned)(((bb*JJ + jt*128 + row) * PP) * 2 + sc * 16);
  }

  f32x4 acc[4][4];
  #pragma unroll
  for (int i = 0; i < 4; i++)
    #pragma unroll
    for (int q = 0; q < 4; q++) acc[i][q] = (f32x4){0.f, 0.f, 0.f, 0.f};

  unsigned ldsw = (unsigned)(wave * 1024);  // wave-uniform LDS byte base (HW adds lane*16)
  const char* pAh = (const char*)Ah;
  const char* pAl = (const char*)Al;
  const char* pYh = (const char*)Yh;
  const char* pYl = (const char*)Yl;

  for (int ps = 0; ps < PP/64; ps++){
    unsigned so = (unsigned)(ps * 128);
    #pragma unroll
    for (int it = 0; it < 4; it++){
      unsigned ld = ldsw + it*4096;
      __builtin_amdgcn_global_load_lds((gas_cuintp)(pAh + aoff[it] + so), (las_uintp)((char*)AhL + ld), 16, 0, 0);
      __builtin_amdgcn_global_load_lds((gas_cuintp)(pAl + aoff[it] + so), (las_uintp)((char*)AlL + ld), 16, 0, 0);
      __builtin_amdgcn_global_load_lds((gas_cuintp)(pYh + yoff[it] + so), (las_uintp)((char*)YhL + ld), 16, 0, 0);
      __builtin_amdgcn_global_load_lds((gas_cuintp)(pYl + yoff[it] + so), (las_uintp)((char*)YlL + ld), 16, 0, 0);
    }
    __syncthreads();
    #pragma unroll
    for (int kk = 0; kk < 2; kk++){
      bf16x8 a_h[4], a_l[4], y_h[4], y_l[4];
      #pragma unroll
      for (int i = 0; i < 4; i++){
        int arow = wr*64 + i*16 + (lane & 15);
        int ach  = ((kk*4) + (lane >> 4)) ^ (arow & 7);
        a_h[i] = *(const bf16x8*)&AhL[arow*64 + ach*8];
        a_l[i] = *(const bf16x8*)&AlL[arow*64 + ach*8];
        int jrow = wc*64 + i*16 + (lane & 15);
        int jch  = ((kk*4) + (lane >> 4)) ^ (jrow & 7);
        y_h[i] = *(const bf16x8*)&YhL[jrow*64 + jch*8];
        y_l[i] = *(const bf16x8*)&YlL[jrow*64 + jch*8];
      }
      #pragma unroll
      for (int i = 0; i < 4; i++)
        #pragma unroll
        for (int q = 0; q < 4; q++){
          acc[i][q] = __builtin_amdgcn_mfma_f32_16x16x32_bf16(a_h[i], y_h[q], acc[i][q], 0, 0, 0);
          acc[i][q] = __builtin_amdgcn_mfma_f32_16x16x32_bf16(a_l[i], y_h[q], acc[i][q], 0, 0, 0);
          acc[i][q] = __builtin_amdgcn_mfma_f32_16x16x32_bf16(a_h[i], y_l[q], acc[i][q], 0, 0, 0);
        }
    }
    __syncthreads();
  }
  // epilogue: relu + store (C/D: col=lane&15, row=(lane>>4)*4+e)
  size_t ob = (size_t)(b0 + bb) * NN * JJ;
  #pragma unroll
  for (int i = 0; i < 4; i++){
    int nbase = nt*128 + wr*64 + i*16 + ((lane >> 4) << 2);
    #pragma unroll
    for (int q = 0; q < 4; q++){
      int j = jt*128 + wc*64 + q*16 + (lane & 15);
      #pragma unroll
      for (int e = 0; e < 4; e++){
        float v = acc[i][q][e];
        v = v > 0.f ? v : 0.f;
        out[ob + (size_t)(nbase + e) * JJ + j] = v;
      }
    }
  }
}

extern "C" void kernel_launch(void* const* d_in, const int* in_sizes, int n_in,
                              void* d_out, int out_size, void* d_ws, size_t ws_size,
                              hipStream_t stream){
  (void)in_sizes; (void)n_in; (void)out_size;
  const float* x     = (const float*)d_in[0];   // [16][1024][64][24]
  const float* stdg  = (const float*)d_in[1];   // [16][1024][1024]
  const float* cheb  = (const float*)d_in[2];   // [3][1024][1024]
  const float* theta = (const float*)d_in[3];   // [3][64][64]
  float* out = (float*)d_out;                   // [16][1024][64][24] viewed as [16][1024][1536]

  const size_t szA_b = (size_t)NN * PP * sizeof(unsigned short);  // 6.29 MB (one of hi/lo)
  const size_t szY_b = (size_t)PP * JJ * sizeof(unsigned short);  // 9.44 MB (one buffer)
  const size_t per_b = 2*szA_b + 3*szY_b;                         // 40.9 MB
  int NB = 16;
  while (NB > 1 && per_b * (size_t)NB > ws_size) NB >>= 1;        // NB in {16,8,4,2,1}

  char* w = (char*)d_ws;
  unsigned short* Ah  = (unsigned short*)w;                        w += szA_b * NB;
  unsigned short* Al  = (unsigned short*)w;                        w += szA_b * NB;
  unsigned short* Yph = (unsigned short*)w;                        w += szY_b * NB;  // [bb][p][j] hi
  unsigned short* Ypl = (unsigned short*)w;                        w += szY_b * NB;  // [bb][p][j] lo
  unsigned short* Yth = (unsigned short*)w;                        w += szY_b * NB;  // [bb][j][p] hi
  unsigned short* Ytl = Yph;  // reuse: Yph fully consumed by first ktransY before this is written

  for (int b0 = 0; b0 < BB; b0 += NB){
    kprepA<<<dim3(16, 16, NB*3),  256, 0, stream>>>(cheb, stdg, Ah, Al, b0);
    kprepY<<<dim3(256, NB),       256, 0, stream>>>(x, theta, Yph, Ypl, b0);
    ktransY<<<dim3(24, 48, NB),   256, 0, stream>>>(Yph, Yth);
    ktransY<<<dim3(24, 48, NB),   256, 0, stream>>>(Ypl, Ytl);
    kgemm<<<dim3(NB*96),          256, 0, stream>>>(Ah, Al, Yth, Ytl, out, b0);
  }
}

// Round 3
// 657.769 us; speedup vs baseline: 1.5548x; 1.5548x over previous
//
#include <hip/hip_runtime.h>
#include <stdint.h>

// Chebyshev GCN: out[b,n,o,t] = relu( sum_{k,c,m} cheb[k,m,n]*STDG[b,m,n]*x[b,m,c,t]*theta[k,c,o] )
// Per b:  C[n, j] = relu( sum_p A[p,n] * Y[p,j] ),  p=(k,m) in [0,3072), j=o*24+t
//   A[p,n] = cheb[k,m,n]*STDG[b,m,n]          (kprepA: bf16, stored [bb][n][p])
//   Y[p,j] = sum_c theta[k,c,o]*x[b,m,c,t]    (kprepY: bf16, written DIRECTLY transposed [bb][j][p])
// Round-3 changes:
//  - single-bf16 operands (round-2 absmax=4.0 matches single-bf16 error exactly -> split
//    corrections were contributing nothing; 4.0 passed validation)
//  - ktransY + Yp intermediate eliminated (saves ~1.2 GB HBM round-trip): kprepY transposes
//    through an LDS tile with 16B-chunk XOR swizzle, 64B-coalesced stores
//  - workspace 15.7 MB/b -> NB=16 single chunk, 3 launches

#define BB   16
#define NN   1024
#define CIN  64
#define TT   24
#define KCH  3
#define COUT 64
#define PP   (KCH*NN)    // 3072 contraction length
#define JJ   (COUT*TT)   // 1536 output columns per n

typedef __attribute__((ext_vector_type(4))) float f32x4;
typedef __attribute__((ext_vector_type(8))) short bf16x8;

typedef __attribute__((address_space(1))) const unsigned int* gas_cuintp;
typedef __attribute__((address_space(3))) unsigned int* las_uintp;

static __device__ __forceinline__ unsigned short f2bf(float f){
  union { float f; unsigned u; } v; v.f = f;
  unsigned r = v.u + 0x7fffu + ((v.u >> 16) & 1u);   // round-to-nearest-even
  return (unsigned short)(r >> 16);
}

// ---------------- K0: A-prep  (masked = cheb*STDG, bf16, transpose to [bb][n][p]) ----------------
__global__ __launch_bounds__(256) void kprepA(const float* __restrict__ cheb,
                                              const float* __restrict__ stdg,
                                              unsigned short* __restrict__ Ah,
                                              int b0){
  int nt = blockIdx.x;             // 16 n-tiles of 64
  int mt = blockIdx.y;             // 16 m-tiles of 64
  int bk = blockIdx.z;             // NB*3 = bb*3+k
  int bb = bk / 3, k = bk - bb * 3;
  int b = b0 + bb;
  __shared__ float alds[64][65];   // [n][m], padded
  int tid = threadIdx.x;
  {
    int rm = tid >> 2;             // m row 0..63
    int nc = (tid & 3) << 4;       // n col group
    const float* cp = cheb + ((size_t)(k*NN + mt*64 + rm))*NN + nt*64 + nc;
    const float* sp = stdg + ((size_t)(b*NN + mt*64 + rm))*NN + nt*64 + nc;
    #pragma unroll
    for (int i = 0; i < 16; i += 4){
      f32x4 cv = *(const f32x4*)(cp + i);
      f32x4 sv = *(const f32x4*)(sp + i);
      #pragma unroll
      for (int q = 0; q < 4; q++) alds[nc + i + q][rm] = cv[q] * sv[q];
    }
  }
  __syncthreads();
  {
    int rn = tid >> 2;             // n row 0..63
    int mc = (tid & 3) << 4;       // m col group
    union { unsigned short s[16]; uint4 v[2]; } hb;
    #pragma unroll
    for (int i = 0; i < 16; i++) hb.s[i] = f2bf(alds[rn][mc + i]);
    size_t ob = ((size_t)(bb*NN + nt*64 + rn))*PP + (size_t)k*NN + mt*64 + mc;
    *(uint4*)(Ah + ob)     = hb.v[0];
    *(uint4*)(Ah + ob + 8) = hb.v[1];
  }
}

// ---------------- K1: Y-prep fused with transpose -> writes [bb][j][p] directly ----------------
// Block: b x (m-slab of 32) x (o-block of 8 -> j-block of 192). 256 threads: (m = tid>>3, o = tid&7).
// LDS: x chunk [32m][8c][24t] f32 (m-stride 196 -> conflict-free b128 reads), theta [3][64][8],
//      ytile [192 j][32 p] bf16 as 4x16B chunks/row with XOR swizzle (write ~2-4 way, read free).
__global__ __launch_bounds__(256) void kprepY(const float* __restrict__ x,
                                              const float* __restrict__ theta,
                                              unsigned short* __restrict__ Yt,
                                              int b0){
  int jb = blockIdx.x;             // 8 o-blocks of 8
  int ms = blockIdx.y;             // 32 m-slabs of 32
  int bb = blockIdx.z;
  int b  = b0 + bb;
  __shared__ float xs[32*196];             // 25088 B (per-m stride 196 floats, 192 used)
  __shared__ float ths[3*64*8];            // 6144 B
  __shared__ unsigned short ytile[192*32]; // 12288 B
  int tid = threadIdx.x;
  int mi = tid >> 3, oi = tid & 7;

  // stage theta slice [3][64 c][8 o]
  for (int i = tid; i < 3*64*8; i += 256){
    int k = i >> 9, rem = i & 511;
    int c = rem >> 3, o = rem & 7;
    ths[i] = theta[k*(CIN*COUT) + c*COUT + jb*8 + o];
  }

  float acc0[24], acc1[24], acc2[24];
  #pragma unroll
  for (int t = 0; t < 24; t++){ acc0[t]=0.f; acc1[t]=0.f; acc2[t]=0.f; }

  const f32x4* xg4 = (const f32x4*)(x + ((size_t)(b*NN + ms*32))*CIN*TT);
  for (int cc = 0; cc < 8; cc++){
    __syncthreads();               // first iter: theta ready; later: xs consumed
    // stage x chunk: per m, floats [cc*192, cc*192+192) = c in [cc*8, cc*8+8), all t
    for (int i4 = tid; i4 < 32*48; i4 += 256){
      int m = i4 / 48, r = i4 - m*48;
      *(f32x4*)&xs[m*196 + r*4] = xg4[m*384 + cc*48 + r];
    }
    __syncthreads();
    for (int c8 = 0; c8 < 8; c8++){
      float xv[24];
      #pragma unroll
      for (int q = 0; q < 6; q++) *(f32x4*)&xv[q*4] = *(const f32x4*)&xs[mi*196 + c8*24 + q*4];
      int cg = cc*8 + c8;
      float t0 = ths[0*512 + cg*8 + oi];
      float t1 = ths[1*512 + cg*8 + oi];
      float t2 = ths[2*512 + cg*8 + oi];
      #pragma unroll
      for (int t = 0; t < 24; t++){
        acc0[t] = fmaf(t0, xv[t], acc0[t]);
        acc1[t] = fmaf(t1, xv[t], acc1[t]);
        acc2[t] = fmaf(t2, xv[t], acc2[t]);
      }
    }
  }

  // transpose epilogue: per k, stage [192 j][32 p] in LDS then 64B-coalesced stores
  #pragma unroll
  for (int k = 0; k < 3; k++){
    const float* a = (k==0) ? acc0 : (k==1) ? acc1 : acc2;  // unroll-constant select
    __syncthreads();               // ytile reuse across k
    #pragma unroll
    for (int t = 0; t < 24; t++){
      int row = oi*24 + t;
      int sw  = (row >> 3) & 3;
      int sc  = (mi >> 3) ^ sw;            // 16B-chunk swizzle
      ytile[row*32 + sc*8 + (mi & 7)] = f2bf(a[t]);
    }
    __syncthreads();
    for (int r = 0; r < 3; r++){
      int i   = tid + r*256;               // 768 = 192 rows x 4 chunks
      int row = i >> 2, c4 = i & 3;
      int sw  = (row >> 3) & 3;
      uint4 v = *(const uint4*)&ytile[row*32 + (c4 ^ sw)*8];
      size_t ob = ((size_t)bb*JJ + (size_t)jb*192 + row)*PP + k*NN + ms*32 + c4*8;
      *(uint4*)(Yt + ob) = v;
    }
  }
}

// ---------------- K2: per-b GEMM  C[n,j] = relu(sum_p A[p,n]*Y[p,j]), single bf16 ----------------
// Tiles: BM=128 (n) x BN=128 (j) x BK=64 (p). 4 waves (2x2), wave-tile 64x64.
// LDS 2 x [128 rows][64 bf16] = 32 KiB, global_load_lds w/ pre-swizzled source (read bank-free).
__global__ __launch_bounds__(256, 2) void kgemm(
    const unsigned short* __restrict__ Ah,
    const unsigned short* __restrict__ Yh,
    float* __restrict__ out, int b0){
  __shared__ unsigned short AsL[128*64];
  __shared__ unsigned short YsL[128*64];
  int orig = blockIdx.x;
  int cpx  = (int)(gridDim.x >> 3);              // grid is NB*96, always % 8 == 0 -> bijective
  int wgid = ((orig & 7) * cpx) + (orig >> 3);   // XCD swizzle
  int bb  = wgid / 96;
  int r96 = wgid - bb*96;
  int nt  = r96 / 12;
  int jt  = r96 - nt*12;
  int tid = threadIdx.x;
  int lane = tid & 63, wave = tid >> 6;
  int wr = wave >> 1, wc = wave & 1;

  // staging: 2 tiles x 1024 chunks(16B); thread handles chunk (tid + it*256) of each tile.
  // source chunk pre-swizzled: sc = c8 ^ (row&7) so LDS slot s holds global chunk s^(row&7).
  unsigned aoff[4], yoff[4];
  #pragma unroll
  for (int it = 0; it < 4; it++){
    int c = tid + it*256;
    int row = c >> 3;
    int sc = (c & 7) ^ (row & 7);
    aoff[it] = (unsigned)(((bb*NN + nt*128 + row) * PP) * 2 + sc * 16);
    yoff[it] = (unsigned)(((bb*JJ + jt*128 + row) * PP) * 2 + sc * 16);
  }

  f32x4 acc[4][4];
  #pragma unroll
  for (int i = 0; i < 4; i++)
    #pragma unroll
    for (int q = 0; q < 4; q++) acc[i][q] = (f32x4){0.f, 0.f, 0.f, 0.f};

  unsigned ldsw = (unsigned)(wave * 1024);  // wave-uniform LDS byte base (HW adds lane*16)
  const char* pA = (const char*)Ah;
  const char* pY = (const char*)Yh;

  for (int ps = 0; ps < PP/64; ps++){
    unsigned so = (unsigned)(ps * 128);
    #pragma unroll
    for (int it = 0; it < 4; it++){
      unsigned ld = ldsw + it*4096;
      __builtin_amdgcn_global_load_lds((gas_cuintp)(pA + aoff[it] + so), (las_uintp)((char*)AsL + ld), 16, 0, 0);
      __builtin_amdgcn_global_load_lds((gas_cuintp)(pY + yoff[it] + so), (las_uintp)((char*)YsL + ld), 16, 0, 0);
    }
    __syncthreads();
    #pragma unroll
    for (int kk = 0; kk < 2; kk++){
      bf16x8 a_f[4], y_f[4];
      #pragma unroll
      for (int i = 0; i < 4; i++){
        int arow = wr*64 + i*16 + (lane & 15);
        int ach  = ((kk*4) + (lane >> 4)) ^ (arow & 7);
        a_f[i] = *(const bf16x8*)&AsL[arow*64 + ach*8];
        int jrow = wc*64 + i*16 + (lane & 15);
        int jch  = ((kk*4) + (lane >> 4)) ^ (jrow & 7);
        y_f[i] = *(const bf16x8*)&YsL[jrow*64 + jch*8];
      }
      #pragma unroll
      for (int i = 0; i < 4; i++)
        #pragma unroll
        for (int q = 0; q < 4; q++)
          acc[i][q] = __builtin_amdgcn_mfma_f32_16x16x32_bf16(a_f[i], y_f[q], acc[i][q], 0, 0, 0);
    }
    __syncthreads();
  }
  // epilogue: relu + store (C/D: col=lane&15, row=(lane>>4)*4+e)
  size_t ob = (size_t)(b0 + bb) * NN * JJ;
  #pragma unroll
  for (int i = 0; i < 4; i++){
    int nbase = nt*128 + wr*64 + i*16 + ((lane >> 4) << 2);
    #pragma unroll
    for (int q = 0; q < 4; q++){
      int j = jt*128 + wc*64 + q*16 + (lane & 15);
      #pragma unroll
      for (int e = 0; e < 4; e++){
        float v = acc[i][q][e];
        v = v > 0.f ? v : 0.f;
        out[ob + (size_t)(nbase + e) * JJ + j] = v;
      }
    }
  }
}

extern "C" void kernel_launch(void* const* d_in, const int* in_sizes, int n_in,
                              void* d_out, int out_size, void* d_ws, size_t ws_size,
                              hipStream_t stream){
  (void)in_sizes; (void)n_in; (void)out_size;
  const float* x     = (const float*)d_in[0];   // [16][1024][64][24]
  const float* stdg  = (const float*)d_in[1];   // [16][1024][1024]
  const float* cheb  = (const float*)d_in[2];   // [3][1024][1024]
  const float* theta = (const float*)d_in[3];   // [3][64][64]
  float* out = (float*)d_out;                   // [16][1024][64][24] viewed as [16][1024][1536]

  const size_t szA_b = (size_t)NN * PP * sizeof(unsigned short);  // 6.29 MB
  const size_t szY_b = (size_t)PP * JJ * sizeof(unsigned short);  // 9.44 MB
  const size_t per_b = szA_b + szY_b;                             // 15.73 MB
  int NB = 16;
  while (NB > 1 && per_b * (size_t)NB > ws_size) NB >>= 1;        // NB in {16,8,4,2,1}

  char* w = (char*)d_ws;
  unsigned short* Ah = (unsigned short*)w;                         w += szA_b * NB;  // [bb][n][p]
  unsigned short* Yt = (unsigned short*)w;                         w += szY_b * NB;  // [bb][j][p]

  for (int b0 = 0; b0 < BB; b0 += NB){
    kprepA<<<dim3(16, 16, NB*3), 256, 0, stream>>>(cheb, stdg, Ah, b0);
    kprepY<<<dim3(8, 32, NB),    256, 0, stream>>>(x, theta, Yt, b0);
    kgemm<<<dim3(NB*96),         256, 0, stream>>>(Ah, Yt, out, b0);
  }
}